// Round 3
// baseline (346.975 us; speedup 1.0000x reference)
//
#include <hip/hip_runtime.h>

#define N_NODES   50000
#define N_HEDGES  100000
#define E_EDGES   800000
#define F_IN      128
#define F_H       64
#define F_OUT     128

#define NT        16      // nodes per tile
#define TPB_TILES 5       // tiles per block: 625 blocks * 5 * 16 = 50000 exactly

// ---------------------------------------------------------------------------
// Kernel 0: binary-search per-node edge ranges in the two sorted receiver
// arrays. offs[r] = first edge index with receiver >= r; offs[N_NODES] = E.
// ---------------------------------------------------------------------------
__global__ __launch_bounds__(256)
void offsets_kernel(const int* __restrict__ recv1, const int* __restrict__ recv2,
                    int* __restrict__ offs1, int* __restrict__ offs2) {
    int t = blockIdx.x * blockDim.x + threadIdx.x;
    const int total = N_NODES + 1;
    if (t < total) {
        int r = t, lo = 0, hi = E_EDGES;
        while (lo < hi) { int mid = (lo + hi) >> 1; if (recv1[mid] < r) lo = mid + 1; else hi = mid; }
        offs1[r] = lo;
    } else if (t < 2 * total) {
        int r = t - total, lo = 0, hi = E_EDGES;
        while (lo < hi) { int mid = (lo + hi) >> 1; if (recv2[mid] < r) lo = mid + 1; else hi = mid; }
        offs2[r] = lo;
    }
}

// ---------------------------------------------------------------------------
// Kernel 1: Acc1[r][f] = sum_{e: recv[e]==r} conv[e] * nf[snd[e]][f]
// 128 threads per node (one per feature) -> each edge is a coalesced 512B row
// read. Also Csum1[r] = sum conv[e] (for the bias term).
// ---------------------------------------------------------------------------
__global__ __launch_bounds__(256)
void gather_nodes_kernel(const float* __restrict__ nf, const int* __restrict__ senders,
                         const float* __restrict__ conv, const int* __restrict__ offs,
                         float* __restrict__ acc_out, float* __restrict__ csum_out) {
    int group = (blockIdx.x << 1) + (threadIdx.x >> 7);   // node id
    int f = threadIdx.x & 127;
    if (group >= N_NODES) return;
    int s = offs[group], e = offs[group + 1];
    float acc = 0.f, cs = 0.f;
    int i = s;
    for (; i + 4 <= e; i += 4) {                           // 4-deep MLP
        int   s0 = senders[i],   s1 = senders[i+1], s2 = senders[i+2], s3 = senders[i+3];
        float c0 = conv[i],      c1 = conv[i+1],    c2 = conv[i+2],    c3 = conv[i+3];
        float v0 = nf[s0 * F_IN + f], v1 = nf[s1 * F_IN + f];
        float v2 = nf[s2 * F_IN + f], v3 = nf[s3 * F_IN + f];
        acc += c0 * v0; acc += c1 * v1; acc += c2 * v2; acc += c3 * v3;
        cs  += c0 + c1 + c2 + c3;
    }
    for (; i < e; ++i) {
        int sn = senders[i]; float c = conv[i];
        acc += c * nf[sn * F_IN + f]; cs += c;
    }
    acc_out[group * F_IN + f] = acc;
    if (f == 0) csum_out[group] = cs;
}

// ---------------------------------------------------------------------------
// Kernel 2: same for hedge pipeline, 64 threads per node (F_H = 64).
// ---------------------------------------------------------------------------
__global__ __launch_bounds__(256)
void gather_hedges_kernel(const float* __restrict__ hf, const int* __restrict__ senders,
                          const float* __restrict__ conv, const int* __restrict__ offs,
                          float* __restrict__ acc_out, float* __restrict__ csum_out) {
    int group = (blockIdx.x << 2) + (threadIdx.x >> 6);
    int f = threadIdx.x & 63;
    if (group >= N_NODES) return;
    int s = offs[group], e = offs[group + 1];
    float acc = 0.f, cs = 0.f;
    int i = s;
    for (; i + 4 <= e; i += 4) {
        int   s0 = senders[i],   s1 = senders[i+1], s2 = senders[i+2], s3 = senders[i+3];
        float c0 = conv[i],      c1 = conv[i+1],    c2 = conv[i+2],    c3 = conv[i+3];
        float v0 = hf[s0 * F_H + f], v1 = hf[s1 * F_H + f];
        float v2 = hf[s2 * F_H + f], v3 = hf[s3 * F_H + f];
        acc += c0 * v0; acc += c1 * v1; acc += c2 * v2; acc += c3 * v3;
        cs  += c0 + c1 + c2 + c3;
    }
    for (; i < e; ++i) {
        int sn = senders[i]; float c = conv[i];
        acc += c * hf[sn * F_H + f]; cs += c;
    }
    acc_out[group * F_H + f] = acc;
    if (f == 0) csum_out[group] = cs;
}

// ---------------------------------------------------------------------------
// Kernel 3 (v3): full-k weights in registers (thread owns feature j; ~192
// weight VGPRs), 16-node tiles double-buffered in LDS. All LDS reads are
// same-address wave broadcasts; staging writes/loads fully coalesced.
// 1536 FMA per thread per tile vs 2 syncs -> compute-bound, latency hidden.
// acc1g aliases outp (safe: tile rows staged before the same rows are
// written; prefetch reads tile i+1, stores write tile i; blocks disjoint).
// ---------------------------------------------------------------------------
__global__ __launch_bounds__(256)
void gemm_tanh_kernel(const float* acc1g,                       // aliases out!
                      const float* __restrict__ acc2g,
                      const float* __restrict__ csum1, const float* __restrict__ csum2,
                      const float* __restrict__ Wm,  const float* __restrict__ bm,
                      const float* __restrict__ Wsc, const float* __restrict__ bs,
                      float* outp) {
    __shared__ float sA1[2][NT][F_IN];   // 16 KB
    __shared__ float sA2[2][NT][F_H];    //  8 KB
    __shared__ float sCs[2][NT][2];      // 256 B

    const int t = threadIdx.x;
    const int j = t & 127;               // output feature
    const int g = t >> 7;                // node half: 0 -> nodes 0..7, 1 -> 8..15

    // --- full-k weight rows into registers ---
    float wm[F_IN];
    #pragma unroll
    for (int k4 = 0; k4 < 32; ++k4) {
        float4 v = *(const float4*)(Wm + j * F_IN + k4 * 4);
        wm[k4*4+0] = v.x; wm[k4*4+1] = v.y; wm[k4*4+2] = v.z; wm[k4*4+3] = v.w;
    }
    float wsr[F_H];
    #pragma unroll
    for (int k4 = 0; k4 < 16; ++k4) {
        float4 v = *(const float4*)(Wsc + j * F_H + k4 * 4);
        wsr[k4*4+0] = v.x; wsr[k4*4+1] = v.y; wsr[k4*4+2] = v.z; wsr[k4*4+3] = v.w;
    }
    const float bmj = bm[j], bsj = bs[j];

    const int tile0 = blockIdx.x * TPB_TILES;

    // coalesced tile staging: consecutive lanes -> consecutive 16B
    auto stage = [&](int buf, int tile) {
        const int nbase = tile * NT;
        #pragma unroll
        for (int r = 0; r < 2; ++r) {
            int fi = r * 256 + t;                  // 512 float4 total
            int n = fi >> 5, k4 = fi & 31;
            *(float4*)&sA1[buf][n][k4*4] = *(const float4*)(acc1g + (nbase+n)*F_IN + k4*4);
        }
        {
            int n = t >> 4, k4 = t & 15;           // 256 float4 total
            *(float4*)&sA2[buf][n][k4*4] = *(const float4*)(acc2g + (nbase+n)*F_H + k4*4);
        }
        if (t < NT)            sCs[buf][t][0]      = csum1[nbase + t];
        else if (t < 2 * NT)   sCs[buf][t - NT][1] = csum2[nbase + t - NT];
    };

    stage(0, tile0);
    int buf = 0;
    #pragma unroll 1
    for (int ti = 0; ti < TPB_TILES; ++ti) {
        __syncthreads();                                   // staging of `buf` done
        if (ti + 1 < TPB_TILES) stage(buf ^ 1, tile0 + ti + 1);
        const int nbase = (tile0 + ti) * NT;
        #pragma unroll
        for (int n = 0; n < 8; ++n) {
            const int nl = g * 8 + n;
            float m0 = 0.f, m1 = 0.f, m2 = 0.f, m3 = 0.f;  // break dep chains
            #pragma unroll
            for (int k4 = 0; k4 < 32; k4 += 4) {
                float4 a0 = *(const float4*)&sA1[buf][nl][(k4+0)*4];
                float4 a1 = *(const float4*)&sA1[buf][nl][(k4+1)*4];
                float4 a2 = *(const float4*)&sA1[buf][nl][(k4+2)*4];
                float4 a3 = *(const float4*)&sA1[buf][nl][(k4+3)*4];
                m0 += wm[(k4+0)*4+0]*a0.x; m0 += wm[(k4+0)*4+1]*a0.y;
                m0 += wm[(k4+0)*4+2]*a0.z; m0 += wm[(k4+0)*4+3]*a0.w;
                m1 += wm[(k4+1)*4+0]*a1.x; m1 += wm[(k4+1)*4+1]*a1.y;
                m1 += wm[(k4+1)*4+2]*a1.z; m1 += wm[(k4+1)*4+3]*a1.w;
                m2 += wm[(k4+2)*4+0]*a2.x; m2 += wm[(k4+2)*4+1]*a2.y;
                m2 += wm[(k4+2)*4+2]*a2.z; m2 += wm[(k4+2)*4+3]*a2.w;
                m3 += wm[(k4+3)*4+0]*a3.x; m3 += wm[(k4+3)*4+1]*a3.y;
                m3 += wm[(k4+3)*4+2]*a3.z; m3 += wm[(k4+3)*4+3]*a3.w;
            }
            float s0 = 0.f, s1 = 0.f;
            #pragma unroll
            for (int k4 = 0; k4 < 16; k4 += 2) {
                float4 a0 = *(const float4*)&sA2[buf][nl][(k4+0)*4];
                float4 a1 = *(const float4*)&sA2[buf][nl][(k4+1)*4];
                s0 += wsr[(k4+0)*4+0]*a0.x; s0 += wsr[(k4+0)*4+1]*a0.y;
                s0 += wsr[(k4+0)*4+2]*a0.z; s0 += wsr[(k4+0)*4+3]*a0.w;
                s1 += wsr[(k4+1)*4+0]*a1.x; s1 += wsr[(k4+1)*4+1]*a1.y;
                s1 += wsr[(k4+1)*4+2]*a1.z; s1 += wsr[(k4+1)*4+3]*a1.w;
            }
            float mt = (m0 + m1) + (m2 + m3) + sCs[buf][nl][0] * bmj;
            float st = (s0 + s1) + sCs[buf][nl][1] * bsj;
            outp[(nbase + nl) * F_OUT + j] = tanhf(mt * st);
        }
        buf ^= 1;
    }
}

// ---------------------------------------------------------------------------
extern "C" void kernel_launch(void* const* d_in, const int* in_sizes, int n_in,
                              void* d_out, int out_size, void* d_ws, size_t ws_size,
                              hipStream_t stream) {
    const float* node_features  = (const float*)d_in[0];
    const float* hedge_features = (const float*)d_in[1];
    const int*   node_senders   = (const int*)d_in[2];
    const int*   node_receivers = (const int*)d_in[3];
    const float* node_conv      = (const float*)d_in[4];
    const int*   h2n_senders    = (const int*)d_in[5];
    const int*   h2n_receivers  = (const int*)d_in[6];
    const float* h2n_conv       = (const float*)d_in[7];
    const float* W_msg          = (const float*)d_in[8];
    const float* b_msg          = (const float*)d_in[9];
    const float* W_scale        = (const float*)d_in[10];
    const float* b_scale        = (const float*)d_in[11];

    float* out = (float*)d_out;
    char*  ws  = (char*)d_ws;

    // ws layout (Acc1 lives in d_out itself)
    float* Acc2  = (float*)(ws);                    // 12,800,000 B
    float* Csum1 = (float*)(ws + 12800000);         //    200,000 B
    float* Csum2 = (float*)(ws + 13000000);         //    200,000 B
    int*   offs1 = (int*)  (ws + 13200000);         //    200,016 B
    int*   offs2 = (int*)  (ws + 13400016);         //    200,016 B
    float* Acc1  = out;

    offsets_kernel<<<(2 * (N_NODES + 1) + 255) / 256, 256, 0, stream>>>(
        node_receivers, h2n_receivers, offs1, offs2);

    gather_nodes_kernel<<<N_NODES / 2, 256, 0, stream>>>(
        node_features, node_senders, node_conv, offs1, Acc1, Csum1);

    gather_hedges_kernel<<<N_NODES / 4, 256, 0, stream>>>(
        hedge_features, h2n_senders, h2n_conv, offs2, Acc2, Csum2);

    gemm_tanh_kernel<<<(N_NODES / (NT * TPB_TILES)), 256, 0, stream>>>(
        Acc1, Acc2, Csum1, Csum2, W_msg, b_msg, W_scale, b_scale, out);
}

// Round 4
// 322.795 us; speedup vs baseline: 1.0749x; 1.0749x over previous
//
#include <hip/hip_runtime.h>

#define N_NODES   50000
#define N_HEDGES  100000
#define E_EDGES   800000
#define F_IN      128
#define F_H       64
#define F_OUT     128

#define NT        16      // nodes per tile
#define TPB_TILES 5       // tiles per block: 625 blocks * 5 * 16 = 50000 exactly

// ---------------------------------------------------------------------------
// Kernel 0: binary-search per-node edge ranges in the two sorted receiver
// arrays. offs[r] = first edge index with receiver >= r; offs[N_NODES] = E.
// ---------------------------------------------------------------------------
__global__ __launch_bounds__(256)
void offsets_kernel(const int* __restrict__ recv1, const int* __restrict__ recv2,
                    int* __restrict__ offs1, int* __restrict__ offs2) {
    int t = blockIdx.x * blockDim.x + threadIdx.x;
    const int total = N_NODES + 1;
    if (t < total) {
        int r = t, lo = 0, hi = E_EDGES;
        while (lo < hi) { int mid = (lo + hi) >> 1; if (recv1[mid] < r) lo = mid + 1; else hi = mid; }
        offs1[r] = lo;
    } else if (t < 2 * total) {
        int r = t - total, lo = 0, hi = E_EDGES;
        while (lo < hi) { int mid = (lo + hi) >> 1; if (recv2[mid] < r) lo = mid + 1; else hi = mid; }
        offs2[r] = lo;
    }
}

// ---------------------------------------------------------------------------
// Kernel 1: one WAVE per node. Lane covers 2 features (float2 = 8B); each
// edge's 512B row read is a single wave instruction. senders/conv are
// wave-uniform -> scalar loads. Acc1[r][f] = sum conv[e]*nf[snd[e]][f].
// ---------------------------------------------------------------------------
__global__ __launch_bounds__(256)
void gather_nodes_kernel(const float* __restrict__ nf, const int* __restrict__ senders,
                         const float* __restrict__ conv, const int* __restrict__ offs,
                         float* __restrict__ acc_out, float* __restrict__ csum_out) {
    const int lane = threadIdx.x & 63;
    const int node = blockIdx.x * 4 + (threadIdx.x >> 6);
    const int s = offs[node], e = offs[node + 1];
    float a0 = 0.f, a1 = 0.f, cs = 0.f;
    const float* base = nf + lane * 2;
    int i = s;
    for (; i + 4 <= e; i += 4) {
        int   s0 = senders[i],   s1 = senders[i+1], s2 = senders[i+2], s3 = senders[i+3];
        float c0 = conv[i],      c1 = conv[i+1],    c2 = conv[i+2],    c3 = conv[i+3];
        float2 v0 = *(const float2*)(base + s0 * F_IN);
        float2 v1 = *(const float2*)(base + s1 * F_IN);
        float2 v2 = *(const float2*)(base + s2 * F_IN);
        float2 v3 = *(const float2*)(base + s3 * F_IN);
        a0 += c0 * v0.x; a1 += c0 * v0.y;
        a0 += c1 * v1.x; a1 += c1 * v1.y;
        a0 += c2 * v2.x; a1 += c2 * v2.y;
        a0 += c3 * v3.x; a1 += c3 * v3.y;
        cs += c0 + c1 + c2 + c3;
    }
    for (; i < e; ++i) {
        int sn = senders[i]; float c = conv[i];
        float2 v = *(const float2*)(base + sn * F_IN);
        a0 += c * v.x; a1 += c * v.y; cs += c;
    }
    *(float2*)(acc_out + node * F_IN + lane * 2) = make_float2(a0, a1);
    if (lane == 0) csum_out[node] = cs;
}

// ---------------------------------------------------------------------------
// Kernel 2: one wave per node, lane covers 1 feature (F_H = 64 = wave size).
// ---------------------------------------------------------------------------
__global__ __launch_bounds__(256)
void gather_hedges_kernel(const float* __restrict__ hf, const int* __restrict__ senders,
                          const float* __restrict__ conv, const int* __restrict__ offs,
                          float* __restrict__ acc_out, float* __restrict__ csum_out) {
    const int lane = threadIdx.x & 63;
    const int node = blockIdx.x * 4 + (threadIdx.x >> 6);
    const int s = offs[node], e = offs[node + 1];
    float a = 0.f, cs = 0.f;
    const float* base = hf + lane;
    int i = s;
    for (; i + 4 <= e; i += 4) {
        int   s0 = senders[i],   s1 = senders[i+1], s2 = senders[i+2], s3 = senders[i+3];
        float c0 = conv[i],      c1 = conv[i+1],    c2 = conv[i+2],    c3 = conv[i+3];
        float v0 = base[s0 * F_H], v1 = base[s1 * F_H];
        float v2 = base[s2 * F_H], v3 = base[s3 * F_H];
        a += c0 * v0; a += c1 * v1; a += c2 * v2; a += c3 * v3;
        cs += c0 + c1 + c2 + c3;
    }
    for (; i < e; ++i) {
        int sn = senders[i]; float c = conv[i];
        a += c * base[sn * F_H]; cs += c;
    }
    acc_out[node * F_H + lane] = a;
    if (lane == 0) csum_out[node] = cs;
}

// ---------------------------------------------------------------------------
// Kernel 3 (v4): split-k weights in registers. Thread = (feature j, k-half h):
// 96 weight VGPRs (fits! round-3's 192 spilled at VGPR_Count=132). Each thread
// computes half-k partials for all 16 tile nodes (1536 FMA vs 2 syncs), halves
// exchange partials via sP[n][j] (float2, conflict-free), each half finishes
// 8 nodes: combine + bias + tanh + coalesced store.
// acc1g aliases outp (safe: stage of tile i+1 reads rows never written by
// this block until tile i+1's epilogue; all reads of a row precede its write).
// ---------------------------------------------------------------------------
__global__ __launch_bounds__(256)
void gemm_tanh_kernel(const float* acc1g,                       // aliases out!
                      const float* __restrict__ acc2g,
                      const float* __restrict__ csum1, const float* __restrict__ csum2,
                      const float* __restrict__ Wm,  const float* __restrict__ bm,
                      const float* __restrict__ Wsc, const float* __restrict__ bs,
                      float* outp) {
    __shared__ float  sA1[2][NT][F_IN];   // 16 KB
    __shared__ float  sA2[2][NT][F_H];    //  8 KB
    __shared__ float  sCs[2][NT][2];      // 256 B
    __shared__ float2 sP[NT][128];        // 16 KB partial-exchange

    const int t = threadIdx.x;
    const int j = t & 127;               // output feature
    const int h = t >> 7;                // k-half

    // --- half-k weight rows into registers (96 floats) ---
    float wm[64];
    const float* wmrow = Wm + j * F_IN + h * 64;
    #pragma unroll
    for (int k4 = 0; k4 < 16; ++k4) {
        float4 v = *(const float4*)(wmrow + k4 * 4);
        wm[k4*4+0] = v.x; wm[k4*4+1] = v.y; wm[k4*4+2] = v.z; wm[k4*4+3] = v.w;
    }
    float wsr[32];
    const float* wsrow = Wsc + j * F_H + h * 32;
    #pragma unroll
    for (int k4 = 0; k4 < 8; ++k4) {
        float4 v = *(const float4*)(wsrow + k4 * 4);
        wsr[k4*4+0] = v.x; wsr[k4*4+1] = v.y; wsr[k4*4+2] = v.z; wsr[k4*4+3] = v.w;
    }
    const float bmj = bm[j], bsj = bs[j];

    const int tile0 = blockIdx.x * TPB_TILES;

    // coalesced tile staging: consecutive lanes -> consecutive 16B
    auto stage = [&](int buf, int tile) {
        const int nbase = tile * NT;
        #pragma unroll
        for (int r = 0; r < 2; ++r) {
            int fi = r * 256 + t;                  // 512 float4 total
            int n = fi >> 5, k4 = fi & 31;
            *(float4*)&sA1[buf][n][k4*4] = *(const float4*)(acc1g + (nbase+n)*F_IN + k4*4);
        }
        {
            int n = t >> 4, k4 = t & 15;           // 256 float4 total
            *(float4*)&sA2[buf][n][k4*4] = *(const float4*)(acc2g + (nbase+n)*F_H + k4*4);
        }
        if (t < NT)            sCs[buf][t][0]      = csum1[nbase + t];
        else if (t < 2 * NT)   sCs[buf][t - NT][1] = csum2[nbase + t - NT];
    };

    stage(0, tile0);
    int buf = 0;
    #pragma unroll 1
    for (int ti = 0; ti < TPB_TILES; ++ti) {
        __syncthreads();                                   // staging of `buf` done
        if (ti + 1 < TPB_TILES) stage(buf ^ 1, tile0 + ti + 1);

        float pm[NT], ps[NT];
        #pragma unroll
        for (int n = 0; n < NT; ++n) {
            const float* a1 = &sA1[buf][n][h * 64];        // wave-uniform addr (broadcast)
            float m0 = 0.f, m1 = 0.f, m2 = 0.f, m3 = 0.f;
            #pragma unroll
            for (int k4 = 0; k4 < 16; k4 += 4) {
                float4 a0 = *(const float4*)(a1 + (k4+0)*4);
                float4 b1 = *(const float4*)(a1 + (k4+1)*4);
                float4 b2 = *(const float4*)(a1 + (k4+2)*4);
                float4 b3 = *(const float4*)(a1 + (k4+3)*4);
                m0 += wm[(k4+0)*4+0]*a0.x; m0 += wm[(k4+0)*4+1]*a0.y;
                m0 += wm[(k4+0)*4+2]*a0.z; m0 += wm[(k4+0)*4+3]*a0.w;
                m1 += wm[(k4+1)*4+0]*b1.x; m1 += wm[(k4+1)*4+1]*b1.y;
                m1 += wm[(k4+1)*4+2]*b1.z; m1 += wm[(k4+1)*4+3]*b1.w;
                m2 += wm[(k4+2)*4+0]*b2.x; m2 += wm[(k4+2)*4+1]*b2.y;
                m2 += wm[(k4+2)*4+2]*b2.z; m2 += wm[(k4+2)*4+3]*b2.w;
                m3 += wm[(k4+3)*4+0]*b3.x; m3 += wm[(k4+3)*4+1]*b3.y;
                m3 += wm[(k4+3)*4+2]*b3.z; m3 += wm[(k4+3)*4+3]*b3.w;
            }
            const float* a2 = &sA2[buf][n][h * 32];
            float s0 = 0.f, s1 = 0.f;
            #pragma unroll
            for (int k4 = 0; k4 < 8; k4 += 2) {
                float4 a0 = *(const float4*)(a2 + (k4+0)*4);
                float4 b1 = *(const float4*)(a2 + (k4+1)*4);
                s0 += wsr[(k4+0)*4+0]*a0.x; s0 += wsr[(k4+0)*4+1]*a0.y;
                s0 += wsr[(k4+0)*4+2]*a0.z; s0 += wsr[(k4+0)*4+3]*a0.w;
                s1 += wsr[(k4+1)*4+0]*b1.x; s1 += wsr[(k4+1)*4+1]*b1.y;
                s1 += wsr[(k4+1)*4+2]*b1.z; s1 += wsr[(k4+1)*4+3]*b1.w;
            }
            pm[n] = (m0 + m1) + (m2 + m3);
            ps[n] = s0 + s1;
        }

        // write partials for the OTHER half's nodes
        const int on = (1 - h) * 8;
        #pragma unroll
        for (int n = 0; n < 8; ++n)
            sP[on + n][j] = make_float2(pm[on + n], ps[on + n]);
        __syncthreads();                                   // partials visible

        // finish own 8 nodes
        const int mn = h * 8;
        const int nbase = (tile0 + ti) * NT;
        #pragma unroll
        for (int n = 0; n < 8; ++n) {
            const int nl = mn + n;
            float2 o  = sP[nl][j];
            float  mt = pm[nl] + o.x + sCs[buf][nl][0] * bmj;
            float  st = ps[nl] + o.y + sCs[buf][nl][1] * bsj;
            outp[(nbase + nl) * F_OUT + j] = tanhf(mt * st);
        }
        buf ^= 1;
    }
}

// ---------------------------------------------------------------------------
extern "C" void kernel_launch(void* const* d_in, const int* in_sizes, int n_in,
                              void* d_out, int out_size, void* d_ws, size_t ws_size,
                              hipStream_t stream) {
    const float* node_features  = (const float*)d_in[0];
    const float* hedge_features = (const float*)d_in[1];
    const int*   node_senders   = (const int*)d_in[2];
    const int*   node_receivers = (const int*)d_in[3];
    const float* node_conv      = (const float*)d_in[4];
    const int*   h2n_senders    = (const int*)d_in[5];
    const int*   h2n_receivers  = (const int*)d_in[6];
    const float* h2n_conv       = (const float*)d_in[7];
    const float* W_msg          = (const float*)d_in[8];
    const float* b_msg          = (const float*)d_in[9];
    const float* W_scale        = (const float*)d_in[10];
    const float* b_scale        = (const float*)d_in[11];

    float* out = (float*)d_out;
    char*  ws  = (char*)d_ws;

    // ws layout (Acc1 lives in d_out itself)
    float* Acc2  = (float*)(ws);                    // 12,800,000 B
    float* Csum1 = (float*)(ws + 12800000);         //    200,000 B
    float* Csum2 = (float*)(ws + 13000000);         //    200,000 B
    int*   offs1 = (int*)  (ws + 13200000);         //    200,016 B
    int*   offs2 = (int*)  (ws + 13400016);         //    200,016 B
    float* Acc1  = out;

    offsets_kernel<<<(2 * (N_NODES + 1) + 255) / 256, 256, 0, stream>>>(
        node_receivers, h2n_receivers, offs1, offs2);

    gather_nodes_kernel<<<N_NODES / 4, 256, 0, stream>>>(
        node_features, node_senders, node_conv, offs1, Acc1, Csum1);

    gather_hedges_kernel<<<N_NODES / 4, 256, 0, stream>>>(
        hedge_features, h2n_senders, h2n_conv, offs2, Acc2, Csum2);

    gemm_tanh_kernel<<<(N_NODES / (NT * TPB_TILES)), 256, 0, stream>>>(
        Acc1, Acc2, Csum1, Csum2, W_msg, b_msg, W_scale, b_scale, out);
}

// Round 5
// 139.541 us; speedup vs baseline: 2.4865x; 2.3133x over previous
//
#include <hip/hip_runtime.h>

#define N_NODES   50000
#define N_HEDGES  100000
#define E_EDGES   800000
#define F_IN      128
#define F_H       64
#define F_OUT     128

typedef __attribute__((ext_vector_type(8))) short short8;
typedef __attribute__((ext_vector_type(4))) float f32x4;

// float -> bf16 (RNE) and back, bit-level (no header dependence)
__device__ __forceinline__ unsigned short f2bf(float f) {
    unsigned int u = __float_as_uint(f);
    return (unsigned short)((u + 0x7fffu + ((u >> 16) & 1u)) >> 16);
}
__device__ __forceinline__ float bf2f(unsigned short h) {
    return __uint_as_float(((unsigned int)h) << 16);
}

// ---------------------------------------------------------------------------
// Kernel 0: per-node edge ranges (binary search in sorted receivers) PLUS
// W -> bf16 hi/lo split conversion (tail blocks).
// ---------------------------------------------------------------------------
__global__ __launch_bounds__(256)
void offsets_kernel(const int* __restrict__ recv1, const int* __restrict__ recv2,
                    int* __restrict__ offs1, int* __restrict__ offs2,
                    const float* __restrict__ Wm, const float* __restrict__ Wsc,
                    unsigned short* __restrict__ wmhi, unsigned short* __restrict__ wmlo,
                    unsigned short* __restrict__ wshi, unsigned short* __restrict__ wslo) {
    int t = blockIdx.x * blockDim.x + threadIdx.x;
    const int total = N_NODES + 1;
    if (t < total) {
        int r = t, lo = 0, hi = E_EDGES;
        while (lo < hi) { int mid = (lo + hi) >> 1; if (recv1[mid] < r) lo = mid + 1; else hi = mid; }
        offs1[r] = lo;
    } else if (t < 2 * total) {
        int r = t - total, lo = 0, hi = E_EDGES;
        while (lo < hi) { int mid = (lo + hi) >> 1; if (recv2[mid] < r) lo = mid + 1; else hi = mid; }
        offs2[r] = lo;
    } else {
        int idx = t - 2 * total;
        if (idx < F_OUT * F_IN) {
            float f = Wm[idx];
            unsigned short h = f2bf(f);
            wmhi[idx] = h; wmlo[idx] = f2bf(f - bf2f(h));
        } else if (idx < F_OUT * F_IN + F_OUT * F_H) {
            int i2 = idx - F_OUT * F_IN;
            float f = Wsc[i2];
            unsigned short h = f2bf(f);
            wshi[i2] = h; wslo[i2] = f2bf(f - bf2f(h));
        }
    }
}

// ---------------------------------------------------------------------------
// Kernel 1: one WAVE per node, lane = 2 features. Accumulate fp32, emit
// packed bf16 hi/lo row into a1pack (== d_out): row n bytes [n*512, n*512+512)
// = [hi row 256B][lo row 256B]. Csum1[n] = sum conv (for bias fold).
// ---------------------------------------------------------------------------
__global__ __launch_bounds__(256)
void gather_nodes_kernel(const float* __restrict__ nf, const int* __restrict__ senders,
                         const float* __restrict__ conv, const int* __restrict__ offs,
                         char* a1pack, float* __restrict__ csum_out) {
    const int lane = threadIdx.x & 63;
    const int node = blockIdx.x * 4 + (threadIdx.x >> 6);
    const int s = offs[node], e = offs[node + 1];
    float a0 = 0.f, a1 = 0.f, cs = 0.f;
    const float* base = nf + lane * 2;
    int i = s;
    for (; i + 4 <= e; i += 4) {
        int   s0 = senders[i],   s1 = senders[i+1], s2 = senders[i+2], s3 = senders[i+3];
        float c0 = conv[i],      c1 = conv[i+1],    c2 = conv[i+2],    c3 = conv[i+3];
        float2 v0 = *(const float2*)(base + s0 * F_IN);
        float2 v1 = *(const float2*)(base + s1 * F_IN);
        float2 v2 = *(const float2*)(base + s2 * F_IN);
        float2 v3 = *(const float2*)(base + s3 * F_IN);
        a0 += c0 * v0.x; a1 += c0 * v0.y;
        a0 += c1 * v1.x; a1 += c1 * v1.y;
        a0 += c2 * v2.x; a1 += c2 * v2.y;
        a0 += c3 * v3.x; a1 += c3 * v3.y;
        cs += c0 + c1 + c2 + c3;
    }
    for (; i < e; ++i) {
        int sn = senders[i]; float c = conv[i];
        float2 v = *(const float2*)(base + sn * F_IN);
        a0 += c * v.x; a1 += c * v.y; cs += c;
    }
    unsigned short h0 = f2bf(a0), h1 = f2bf(a1);
    unsigned short l0 = f2bf(a0 - bf2f(h0)), l1 = f2bf(a1 - bf2f(h1));
    unsigned int* hp = (unsigned int*)(a1pack + (size_t)node * 512);
    unsigned int* lp = (unsigned int*)(a1pack + (size_t)node * 512 + 256);
    hp[lane] = (unsigned int)h0 | ((unsigned int)h1 << 16);
    lp[lane] = (unsigned int)l0 | ((unsigned int)l1 << 16);
    if (lane == 0) csum_out[node] = cs;
}

// ---------------------------------------------------------------------------
// Kernel 2: one wave per node, lane = 1 feature (F_H=64). Packed bf16 hi/lo
// row into a2pack: row n bytes [n*256, +256) = [hi 128B][lo 128B].
// ---------------------------------------------------------------------------
__global__ __launch_bounds__(256)
void gather_hedges_kernel(const float* __restrict__ hf, const int* __restrict__ senders,
                          const float* __restrict__ conv, const int* __restrict__ offs,
                          char* __restrict__ a2pack, float* __restrict__ csum_out) {
    const int lane = threadIdx.x & 63;
    const int node = blockIdx.x * 4 + (threadIdx.x >> 6);
    const int s = offs[node], e = offs[node + 1];
    float a = 0.f, cs = 0.f;
    const float* base = hf + lane;
    int i = s;
    for (; i + 4 <= e; i += 4) {
        int   s0 = senders[i],   s1 = senders[i+1], s2 = senders[i+2], s3 = senders[i+3];
        float c0 = conv[i],      c1 = conv[i+1],    c2 = conv[i+2],    c3 = conv[i+3];
        float v0 = base[s0 * F_H], v1 = base[s1 * F_H];
        float v2 = base[s2 * F_H], v3 = base[s3 * F_H];
        a += c0 * v0; a += c1 * v1; a += c2 * v2; a += c3 * v3;
        cs += c0 + c1 + c2 + c3;
    }
    for (; i < e; ++i) {
        int sn = senders[i]; float c = conv[i];
        a += c * base[sn * F_H]; cs += c;
    }
    unsigned short h = f2bf(a);
    unsigned short l = f2bf(a - bf2f(h));
    ((unsigned short*)(a2pack + (size_t)node * 256))[lane]       = h;
    ((unsigned short*)(a2pack + (size_t)node * 256 + 128))[lane] = l;
    if (lane == 0) csum_out[node] = cs;
}

// ---------------------------------------------------------------------------
// Kernel 3 (v5, MFMA): C1 = A1@Wm^T, C2 = A2@Ws^T via bf16 hi/lo split
// (Ah*Wh + Ah*Wl + Al*Wh), out = tanh((C1+cs1*bm)*(C2+cs2*bs)).
// Block = 4 waves x 64 nodes (4 tiles of 16). Wave owns 32 features
// (2 j-tiles); W-frags resident in 96 VGPRs. A staged in 12KB LDS with XOR
// swizzle (chunk^row) -> 2-way max bank aliasing (free).
// Fragment robustness: A-frag and B-frag use the SAME (group,elem)->k map,
// so any true HW k-permutation cancels (MFMA A/B symmetry). Only the C/D
// layout (col=lane&15, row=(lane>>4)*4+reg) is load-bearing (HW-verified).
// a1pack aliases outp: block reads rows [n0,n0+16) into LDS before the
// barrier; stores to those rows happen after it. Blocks disjoint.
// ---------------------------------------------------------------------------
__global__ __launch_bounds__(256)
void gemm_tanh_kernel(const char* a1pack,                       // aliases out!
                      const char* __restrict__ a2pack,
                      const float* __restrict__ csum1, const float* __restrict__ csum2,
                      const unsigned short* __restrict__ wmhi, const unsigned short* __restrict__ wmlo,
                      const unsigned short* __restrict__ wshi, const unsigned short* __restrict__ wslo,
                      const float* __restrict__ bm, const float* __restrict__ bs,
                      float* outp) {
    __shared__ __align__(16) char sA1[16 * 512];   // 8 KB (hi|lo per row)
    __shared__ __align__(16) char sA2[16 * 256];   // 4 KB
    __shared__ float sCs[16][2];

    const int t   = threadIdx.x;
    const int wid = t >> 6;
    const int l   = t & 63;
    const int g   = l >> 4;     // lane group (k-groups)
    const int jl  = l & 15;     // A-frag row / B-frag row / D col

    // ---- W fragments in registers (per wave: features [wid*32, wid*32+32)) ----
    short8 wm_h[2][4], wm_l[2][4], ws_h[2][2], ws_l[2][2];
    float bmj[2], bsj[2];
    #pragma unroll
    for (int jt = 0; jt < 2; ++jt) {
        const int j = wid * 32 + jt * 16 + jl;
        #pragma unroll
        for (int ks = 0; ks < 4; ++ks) {
            wm_h[jt][ks] = *(const short8*)(wmhi + j * F_IN + ks * 32 + g * 8);
            wm_l[jt][ks] = *(const short8*)(wmlo + j * F_IN + ks * 32 + g * 8);
        }
        #pragma unroll
        for (int ks = 0; ks < 2; ++ks) {
            ws_h[jt][ks] = *(const short8*)(wshi + j * F_H + ks * 32 + g * 8);
            ws_l[jt][ks] = *(const short8*)(wslo + j * F_H + ks * 32 + g * 8);
        }
        bmj[jt] = bm[j]; bsj[jt] = bs[j];
    }

    #pragma unroll 1
    for (int ns = 0; ns < 4; ++ns) {
        const int n0 = blockIdx.x * 64 + ns * 16;
        // ---- stage tile (coalesced global, XOR-swizzled LDS) ----
        #pragma unroll
        for (int it = 0; it < 2; ++it) {
            int fi = (it << 8) + t;
            int ci = fi & 31, row = fi >> 5;
            int nsrc = min(n0 + row, N_NODES - 1);
            float4 v = *(const float4*)(a1pack + (size_t)nsrc * 512 + ci * 16);
            *(float4*)(sA1 + row * 512 + (((unsigned)ci << 4) ^ (((unsigned)row & 7) << 4))) = v;
        }
        {
            int ci = t & 15, row = t >> 4;
            int nsrc = min(n0 + row, N_NODES - 1);
            float4 v = *(const float4*)(a2pack + (size_t)nsrc * 256 + ci * 16);
            *(float4*)(sA2 + row * 256 + (((unsigned)ci << 4) ^ (((unsigned)row & 7) << 4))) = v;
        }
        if (t < 16)      sCs[t][0]      = csum1[min(n0 + t, N_NODES - 1)];
        else if (t < 32) sCs[t - 16][1] = csum2[min(n0 + t - 16, N_NODES - 1)];
        __syncthreads();

        // ---- A fragments (shared across both j-tiles) ----
        short8 a1h[4], a1l[4], a2h[2], a2l[2];
        const unsigned sw = ((unsigned)jl & 7) << 4;
        #pragma unroll
        for (int ks = 0; ks < 4; ++ks) {
            unsigned cc = (((unsigned)(4 * ks + g)) << 4) ^ sw;
            a1h[ks] = *(const short8*)(sA1 + jl * 512 + cc);
            a1l[ks] = *(const short8*)(sA1 + jl * 512 + 256 + cc);
        }
        #pragma unroll
        for (int ks = 0; ks < 2; ++ks) {
            unsigned cc = (((unsigned)(4 * ks + g)) << 4) ^ sw;
            a2h[ks] = *(const short8*)(sA2 + jl * 256 + cc);
            a2l[ks] = *(const short8*)(sA2 + jl * 256 + 128 + cc);
        }

        // ---- MFMA + epilogue per j-tile ----
        #pragma unroll
        for (int jt = 0; jt < 2; ++jt) {
            f32x4 c1 = {0.f, 0.f, 0.f, 0.f}, c2 = {0.f, 0.f, 0.f, 0.f};
            #pragma unroll
            for (int ks = 0; ks < 4; ++ks) {
                c1 = __builtin_amdgcn_mfma_f32_16x16x32_bf16(a1h[ks], wm_h[jt][ks], c1, 0, 0, 0);
                c1 = __builtin_amdgcn_mfma_f32_16x16x32_bf16(a1h[ks], wm_l[jt][ks], c1, 0, 0, 0);
                c1 = __builtin_amdgcn_mfma_f32_16x16x32_bf16(a1l[ks], wm_h[jt][ks], c1, 0, 0, 0);
            }
            #pragma unroll
            for (int ks = 0; ks < 2; ++ks) {
                c2 = __builtin_amdgcn_mfma_f32_16x16x32_bf16(a2h[ks], ws_h[jt][ks], c2, 0, 0, 0);
                c2 = __builtin_amdgcn_mfma_f32_16x16x32_bf16(a2h[ks], ws_l[jt][ks], c2, 0, 0, 0);
                c2 = __builtin_amdgcn_mfma_f32_16x16x32_bf16(a2l[ks], ws_h[jt][ks], c2, 0, 0, 0);
            }
            const int j = wid * 32 + jt * 16 + jl;
            #pragma unroll
            for (int r = 0; r < 4; ++r) {
                int row  = g * 4 + r;
                int node = n0 + row;
                if (node < N_NODES) {
                    float v1 = c1[r] + sCs[row][0] * bmj[jt];
                    float v2 = c2[r] + sCs[row][1] * bsj[jt];
                    outp[(size_t)node * F_OUT + j] = tanhf(v1 * v2);
                }
            }
        }
        __syncthreads();   // LDS reuse guard
    }
}

// ---------------------------------------------------------------------------
extern "C" void kernel_launch(void* const* d_in, const int* in_sizes, int n_in,
                              void* d_out, int out_size, void* d_ws, size_t ws_size,
                              hipStream_t stream) {
    const float* node_features  = (const float*)d_in[0];
    const float* hedge_features = (const float*)d_in[1];
    const int*   node_senders   = (const int*)d_in[2];
    const int*   node_receivers = (const int*)d_in[3];
    const float* node_conv      = (const float*)d_in[4];
    const int*   h2n_senders    = (const int*)d_in[5];
    const int*   h2n_receivers  = (const int*)d_in[6];
    const float* h2n_conv       = (const float*)d_in[7];
    const float* W_msg          = (const float*)d_in[8];
    const float* b_msg          = (const float*)d_in[9];
    const float* W_scale        = (const float*)d_in[10];
    const float* b_scale        = (const float*)d_in[11];

    float* out = (float*)d_out;
    char*  ws  = (char*)d_ws;

    // ws layout
    char*  A2pack = ws;                                      // 12,800,000 B
    float* Csum1  = (float*)(ws + 12800000);                 //    200,000 B
    float* Csum2  = (float*)(ws + 13000000);                 //    200,000 B
    int*   offs1  = (int*)  (ws + 13200000);                 //    200,016 B
    int*   offs2  = (int*)  (ws + 13400016);                 //    200,016 B
    unsigned short* wmhi = (unsigned short*)(ws + 13600032); //     32,768 B
    unsigned short* wmlo = (unsigned short*)(ws + 13632800); //     32,768 B
    unsigned short* wshi = (unsigned short*)(ws + 13665568); //     16,384 B
    unsigned short* wslo = (unsigned short*)(ws + 13681952); //     16,384 B
    char*  A1pack = (char*)d_out;                            // packed bf16 hi/lo, aliases out

    // offsets + W split-conversion: 2*(N+1) + 24576 work items
    offsets_kernel<<<(2 * (N_NODES + 1) + F_OUT * (F_IN + F_H) + 255) / 256, 256, 0, stream>>>(
        node_receivers, h2n_receivers, offs1, offs2,
        W_msg, W_scale, wmhi, wmlo, wshi, wslo);

    gather_nodes_kernel<<<N_NODES / 4, 256, 0, stream>>>(
        node_features, node_senders, node_conv, offs1, A1pack, Csum1);

    gather_hedges_kernel<<<N_NODES / 4, 256, 0, stream>>>(
        hedge_features, h2n_senders, h2n_conv, offs2, A2pack, Csum2);

    gemm_tanh_kernel<<<(N_NODES + 63) / 64, 256, 0, stream>>>(
        A1pack, A2pack, Csum1, Csum2, wmhi, wmlo, wshi, wslo,
        b_msg, b_scale, out);
}